// Round 3
// baseline (9198.314 us; speedup 1.0000x reference)
//
#include <hip/hip_runtime.h>
#include <stdint.h>

#define TT 256
#define BB 64
#define DD 1024
#define HH 1024
#define G3 3072

typedef unsigned long long ull;
typedef __attribute__((ext_vector_type(8))) short short8;
typedef __attribute__((ext_vector_type(4))) float f32x4;

__device__ __forceinline__ unsigned short f2bf(float f) {
  union { float f; unsigned int i; } v; v.f = f;
  unsigned int x = v.i;
  return (unsigned short)((x + 0x7fffu + ((x >> 16) & 1u)) >> 16);
}
__device__ __forceinline__ float bf2f(unsigned short u) {
  union { unsigned int i; float f; } v; v.i = ((unsigned int)u) << 16; return v.f;
}
__device__ __forceinline__ f32x4 mfma16(short8 a, short8 b, f32x4 c) {
  return __builtin_amdgcn_mfma_f32_16x16x32_bf16(a, b, c, 0, 0, 0);
}
__device__ __forceinline__ void gload_lds16(const void* g, void* l) {
  __builtin_amdgcn_global_load_lds((const __attribute__((address_space(1))) void*)g,
                                   (__attribute__((address_space(3))) void*)l,
                                   16, 0, 0);
}

// ---------------- f32 -> bf16 convert (vectorized) ----------------
__global__ void k_cvt_bf16(const float* __restrict__ in, unsigned short* __restrict__ out, int n4) {
  int i = blockIdx.x * blockDim.x + threadIdx.x;
  int stride = gridDim.x * blockDim.x;
  for (; i < n4; i += stride) {
    float4 v = ((const float4*)in)[i];
    ushort4 o;
    o.x = f2bf(v.x); o.y = f2bf(v.y); o.z = f2bf(v.z); o.w = f2bf(v.w);
    ((ushort4*)out)[i] = o;
  }
}

// ---------------- context projections + bias fold: E[64][3072] ----------------
__global__ __launch_bounds__(256) void k_ctx(
    const unsigned short* __restrict__ cjb, const unsigned short* __restrict__ heb,
    const unsigned short* __restrict__ Wchb, const unsigned short* __restrict__ Wzhb,
    const float* __restrict__ b_ih, const float* __restrict__ b_hh,
    const float* __restrict__ b_ch, const float* __restrict__ b_zh,
    float* __restrict__ E) {
  __shared__ f32x4 red[4][4][64];   // 16 KB
  int n0 = blockIdx.x * 16;         // 192 blocks
  int tid = threadIdx.x;
  int w = tid >> 6, l = tid & 63, lo = l & 15, hi = l >> 4;
  f32x4 acc[4];
#pragma unroll
  for (int r = 0; r < 4; r++) acc[r] = (f32x4){0.f, 0.f, 0.f, 0.f};
#pragma unroll 4
  for (int kk = 0; kk < 16; kk++) {
    int k = w * 512 + kk * 32;
    const unsigned short* Asrc = (k < 1024) ? cjb : heb;
    const unsigned short* Bsrc = (k < 1024) ? Wchb : Wzhb;
    int kw = (k < 1024) ? k : (k - 1024);
    int kof = kw + hi * 8;
    short8 bf = *(const short8*)(Bsrc + (size_t)(n0 + lo) * 1024 + kof);
#pragma unroll
    for (int r = 0; r < 4; r++) {
      short8 af = *(const short8*)(Asrc + (size_t)(r * 16 + lo) * 1024 + kof);
      acc[r] = mfma16(af, bf, acc[r]);
    }
  }
#pragma unroll
  for (int r = 0; r < 4; r++) red[w][r][l] = acc[r];
  __syncthreads();
  f32x4 s = red[0][w][l];
#pragma unroll
  for (int w2 = 1; w2 < 4; w2++) {
    f32x4 p = red[w2][w][l];
    s[0] += p[0]; s[1] += p[1]; s[2] += p[2]; s[3] += p[3];
  }
  int g = n0 + lo;
  float bias = b_ih[g] + b_ch[g] + b_zh[g] + ((g < 2048) ? b_hh[g] : 0.0f);
#pragma unroll
  for (int j = 0; j < 4; j++) {
    int b = w * 16 + hi * 4 + j;
    E[(size_t)b * G3 + g] = s[j] + bias;
  }
}

// ---------------- gi GEMM + E fold: giE[t*64+b][g] = X@Wih^T + E[b][g] (bf16) --------
__global__ __launch_bounds__(256) void k_gemm_gi(
    const unsigned short* __restrict__ Xb,   // [16384][1024] bf16
    const unsigned short* __restrict__ Wb,   // [3072][1024] bf16
    const float* __restrict__ E,             // [64][3072] f32
    unsigned short* __restrict__ gi) {       // [16384][3072] bf16
  __shared__ unsigned short As[128 * 32];
  __shared__ unsigned short Bs[128 * 32];
  int bid = blockIdx.x;
  int mt = bid & 127;
  int nt = bid >> 7;
  int m0 = mt * 128, n0 = nt * 128;
  int tid = threadIdx.x;
  int w = tid >> 6, l = tid & 63, lo = l & 15, hi = l >> 4;
  int wr = w >> 1, wc = w & 1;
  f32x4 acc[4][4];
#pragma unroll
  for (int i = 0; i < 4; i++)
#pragma unroll
    for (int j = 0; j < 4; j++) acc[i][j] = (f32x4){0.f, 0.f, 0.f, 0.f};
  int srow = tid >> 2;
  int scol = (tid & 3) * 8;
  for (int kt = 0; kt < 32; kt++) {
    int k0 = kt * 32;
    __syncthreads();
    gload_lds16(Xb + (size_t)(m0 + srow) * 1024 + k0 + scol, As + srow * 32 + scol);
    gload_lds16(Xb + (size_t)(m0 + 64 + srow) * 1024 + k0 + scol, As + (64 + srow) * 32 + scol);
    gload_lds16(Wb + (size_t)(n0 + srow) * 1024 + k0 + scol, Bs + srow * 32 + scol);
    gload_lds16(Wb + (size_t)(n0 + 64 + srow) * 1024 + k0 + scol, Bs + (64 + srow) * 32 + scol);
    asm volatile("s_waitcnt vmcnt(0)" ::: "memory");
    __syncthreads();
    short8 a[4], b[4];
#pragma unroll
    for (int i = 0; i < 4; i++) a[i] = *(const short8*)(As + (wr * 64 + i * 16 + lo) * 32 + hi * 8);
#pragma unroll
    for (int i = 0; i < 4; i++) b[i] = *(const short8*)(Bs + (wc * 64 + i * 16 + lo) * 32 + hi * 8);
#pragma unroll
    for (int i = 0; i < 4; i++)
#pragma unroll
      for (int j = 0; j < 4; j++) acc[i][j] = mfma16(a[i], b[j], acc[i][j]);
  }
#pragma unroll
  for (int i = 0; i < 4; i++)
#pragma unroll
    for (int j = 0; j < 4; j++)
#pragma unroll
      for (int e = 0; e < 4; e++) {
        int r = m0 + wr * 64 + i * 16 + hi * 4 + e;
        int c = n0 + wc * 64 + j * 16 + lo;
        float v = acc[i][j][e] + E[(size_t)(r & 63) * G3 + c];
        gi[(size_t)r * G3 + c] = f2bf(v);
      }
}

// ---------------- persistent recurrence kernel ----------------
// 64 wgs x 1024 thr. wg cs owns h cols [cs*16,+16). 16 waves = (rt 0..3) x (kq 0..3):
// row-tile rt*16, K-slice kq*256. Updaters = kq==0.
// NO release/acquire anywhere in the hot loop: h exchange + barrier are relaxed
// agent atomics (MALL is the single coherence point); ordering = s_waitcnt vmcnt(0)
// (stores complete at MALL) before the relaxed counter RMW.
// Barrier: per-step counters ctr[t][rt] (4 lines, 64B apart, 64 adds each);
// every wave spins directly with relaxed loads.
__global__ __launch_bounds__(1024) void k_rnn(
    const unsigned short* __restrict__ giE,   // [256*64][3072] bf16 (incl E)
    const unsigned short* __restrict__ Whhb,  // [3072][1024] bf16
    const float* __restrict__ b_hh,
    const float* __restrict__ h0,
    const int* __restrict__ length,
    unsigned short* __restrict__ hbuf,        // [2][64][1024] bf16
    float* __restrict__ h0row,                // [2][1024] f32 (exact h[0] row)
    float* __restrict__ out,                  // [256][64][1024] f32
    float* __restrict__ hn,                   // [64][1024] f32
    unsigned int* __restrict__ ctr) {         // [256][4][16] uints (64B-spaced lines)
  __shared__ f32x4 red[16 * 3 * 64];          // 48 KB
  const int cs = blockIdx.x;
  const int j0 = cs * 16;
  const int tid = threadIdx.x;
  const int w = tid >> 6, l = tid & 63, lo = l & 15, hi = l >> 4;
  const int rt = w >> 2, kq = w & 3;
  const bool upd = (kq == 0);
  const int col = j0 + lo;
  const int rowbase = rt * 16;

  const unsigned short* wrp0 = Whhb + (size_t)col * 1024;
  const unsigned short* wrp1 = Whhb + (size_t)(1024 + col) * 1024;
  const unsigned short* wrp2 = Whhb + (size_t)(2048 + col) * 1024;
  const float bhhn = b_hh[2048 + col];

  float hown[4] = {0.f, 0.f, 0.f, 0.f};
  float gir[3][4];
  int len4[4] = {0, 0, 0, 0};

  // ---- init: load h0 state, publish h(0), signal ctr[0] ----
  if (upd) {
#pragma unroll
    for (int j = 0; j < 4; j++) {
      int b = rowbase + hi * 4 + j;
      hown[j] = h0[(size_t)b * 1024 + col];
      len4[j] = length[b];
    }
#pragma unroll
    for (int j = 0; j < 4; j++) {
      unsigned int mine = f2bf(hown[j]);
      unsigned int oth = __shfl_xor(mine, 1, 64);
      if (!(lo & 1)) {
        int b = rowbase + hi * 4 + j;
        __hip_atomic_store((unsigned int*)(hbuf + (size_t)b * 1024 + j0 + lo),
                           mine | (oth << 16), __ATOMIC_RELAXED, __HIP_MEMORY_SCOPE_AGENT);
      }
    }
    if (rt == 0 && hi == 0)
      __hip_atomic_store(&h0row[col], hown[0], __ATOMIC_RELAXED, __HIP_MEMORY_SCOPE_AGENT);
    asm volatile("s_waitcnt vmcnt(0)" ::: "memory");
    if (l == 0)
      __hip_atomic_fetch_add(&ctr[rt * 16], 1u, __ATOMIC_RELAXED, __HIP_MEMORY_SCOPE_AGENT);
  }

  for (int t = 0; t < TT; t++) {
    // ---- 1. prefetch gi(t) (plain cached loads; latency hides under spin+MFMA) ----
    if (upd) {
      const unsigned short* gb = giE + (size_t)t * 64 * G3;
#pragma unroll
      for (int s = 0; s < 3; s++)
#pragma unroll
        for (int j = 0; j < 4; j++)
          gir[s][j] = bf2f(gb[(size_t)(rowbase + hi * 4 + j) * G3 + s * 1024 + col]);
    }
    // ---- 2. spin: every wave waits for all 4 counter lines of step t to hit 64 ----
    {
      const unsigned int* cb = ctr + (size_t)t * 64 + (l & 3) * 16;
      for (;;) {
        unsigned int v = __hip_atomic_load(cb, __ATOMIC_RELAXED, __HIP_MEMORY_SCOPE_AGENT);
        if (__all(v >= 64u)) break;
        __builtin_amdgcn_s_sleep(1);
      }
    }
    float h0p = 0.f;
    if (upd)
      h0p = __hip_atomic_load(&h0row[(t & 1) * 1024 + col], __ATOMIC_RELAXED, __HIP_MEMORY_SCOPE_AGENT);
    // ---- 3. partial GEMM on h(t) ----
    const unsigned short* hb = hbuf + (size_t)(t & 1) * (BB * 1024);
    f32x4 a0 = {0.f, 0.f, 0.f, 0.f}, a1 = a0, a2 = a0;
#pragma unroll
    for (int kk = 0; kk < 8; kk++) {
      int k = kq * 256 + kk * 32 + hi * 8;
      const unsigned short* hp = hb + (size_t)(rowbase + lo) * 1024 + k;
      union { ull u[2]; short8 v; } a;
      a.u[0] = __hip_atomic_load((const ull*)hp, __ATOMIC_RELAXED, __HIP_MEMORY_SCOPE_AGENT);
      a.u[1] = __hip_atomic_load((const ull*)(hp + 4), __ATOMIC_RELAXED, __HIP_MEMORY_SCOPE_AGENT);
      short8 b0 = *(const short8*)(wrp0 + k);
      short8 b1 = *(const short8*)(wrp1 + k);
      short8 b2 = *(const short8*)(wrp2 + k);
      a0 = mfma16(a.v, b0, a0);
      a1 = mfma16(a.v, b1, a1);
      a2 = mfma16(a.v, b2, a2);
    }
    red[(w * 3 + 0) * 64 + l] = a0;
    red[(w * 3 + 1) * 64 + l] = a1;
    red[(w * 3 + 2) * 64 + l] = a2;
    __syncthreads();
    // ---- 4. updaters: reduce + gates + publish h(t+1) + signal ----
    if (upd) {
      f32x4 fin[3];
#pragma unroll
      for (int s = 0; s < 3; s++) {
        f32x4 v = red[((rt * 4 + 0) * 3 + s) * 64 + l];
#pragma unroll
        for (int kq2 = 1; kq2 < 4; kq2++) {
          f32x4 p = red[((rt * 4 + kq2) * 3 + s) * 64 + l];
          v[0] += p[0]; v[1] += p[1]; v[2] += p[2]; v[3] += p[3];
        }
        fin[s] = v;
      }
      float hv[4];
#pragma unroll
      for (int j = 0; j < 4; j++) {
        float R = fin[0][j] + gir[0][j];
        float I = fin[1][j] + gir[1][j];
        float rg = 1.f / (1.f + __expf(-R));
        float ig = 1.f / (1.f + __expf(-I));
        float nx = gir[2][j] + rg * (fin[2][j] + bhhn);
        nx = fminf(15.f, fmaxf(-15.f, nx));
        float e2 = __expf(2.f * nx);
        float ng = (e2 - 1.f) / (e2 + 1.f);
        float hy = ng + ig * (hown[j] - ng);
        float res = (t < len4[j]) ? hy : h0p;
        hv[j] = res;
        hown[j] = res;
        int b = rowbase + hi * 4 + j;
        out[(size_t)t * (BB * HH) + (size_t)b * 1024 + col] = res;
        if (t == TT - 1) hn[(size_t)b * 1024 + col] = res;
      }
      if (t < TT - 1) {
        unsigned short* dst = hbuf + (size_t)((t + 1) & 1) * (BB * 1024);
#pragma unroll
        for (int j = 0; j < 4; j++) {
          unsigned int mine = f2bf(hv[j]);
          unsigned int oth = __shfl_xor(mine, 1, 64);
          if (!(lo & 1)) {
            int b = rowbase + hi * 4 + j;
            __hip_atomic_store((unsigned int*)(dst + (size_t)b * 1024 + j0 + lo),
                               mine | (oth << 16), __ATOMIC_RELAXED, __HIP_MEMORY_SCOPE_AGENT);
          }
        }
        if (rt == 0 && hi == 0)
          __hip_atomic_store(&h0row[((t + 1) & 1) * 1024 + col], hv[0],
                             __ATOMIC_RELAXED, __HIP_MEMORY_SCOPE_AGENT);
        // stores complete at MALL before the relaxed signal -> no fence needed
        asm volatile("s_waitcnt vmcnt(0)" ::: "memory");
        if (l == 0)
          __hip_atomic_fetch_add(&ctr[(size_t)(t + 1) * 64 + rt * 16], 1u,
                                 __ATOMIC_RELAXED, __HIP_MEMORY_SCOPE_AGENT);
      }
    }
  }
}

// ---------------- host ----------------
extern "C" void kernel_launch(void* const* d_in, const int* in_sizes, int n_in,
                              void* d_out, int out_size, void* d_ws, size_t ws_size,
                              hipStream_t stream) {
  const float* input_ = (const float*)d_in[0];
  const int* length   = (const int*)d_in[1];
  const float* h0     = (const float*)d_in[2];
  const float* cj     = (const float*)d_in[3];
  const float* he     = (const float*)d_in[4];
  const float* w_ih   = (const float*)d_in[5];
  const float* w_hh   = (const float*)d_in[6];
  const float* w_ch   = (const float*)d_in[7];
  const float* w_zh   = (const float*)d_in[8];
  const float* b_ih   = (const float*)d_in[9];
  const float* b_hh   = (const float*)d_in[10];
  const float* b_ch   = (const float*)d_in[11];
  const float* b_zh   = (const float*)d_in[12];

  char* ws = (char*)d_ws;
  const size_t OFF_CTR   = 0;          // 65536 B: [256][4][16] uints
  const size_t OFF_H0ROW = 65536;      // 8192 B
  const size_t OFF_XB    = 131072;
  const size_t OFF_WIHB  = OFF_XB + 33554432ull;
  const size_t OFF_WHHB  = OFF_WIHB + 6291456ull;
  const size_t OFF_WCHB  = OFF_WHHB + 6291456ull;
  const size_t OFF_WZHB  = OFF_WCHB + 6291456ull;
  const size_t OFF_CJB   = OFF_WZHB + 6291456ull;
  const size_t OFF_HEB   = OFF_CJB + 131072ull;
  const size_t OFF_E     = OFF_HEB + 131072ull;
  const size_t OFF_GI    = OFF_E + 786432ull;
  const size_t OFF_HBUF  = OFF_GI + 100663296ull;

  unsigned int* ctr     = (unsigned int*)(ws + OFF_CTR);
  float* h0row          = (float*)(ws + OFF_H0ROW);
  unsigned short* Xb    = (unsigned short*)(ws + OFF_XB);
  unsigned short* Wihb  = (unsigned short*)(ws + OFF_WIHB);
  unsigned short* Whhb  = (unsigned short*)(ws + OFF_WHHB);
  unsigned short* Wchb  = (unsigned short*)(ws + OFF_WCHB);
  unsigned short* Wzhb  = (unsigned short*)(ws + OFF_WZHB);
  unsigned short* cjb   = (unsigned short*)(ws + OFF_CJB);
  unsigned short* heb   = (unsigned short*)(ws + OFF_HEB);
  float* E              = (float*)(ws + OFF_E);
  unsigned short* gi    = (unsigned short*)(ws + OFF_GI);
  unsigned short* hbuf  = (unsigned short*)(ws + OFF_HBUF);

  float* out = (float*)d_out;
  float* hn  = out + 16777216;   // T*B*H

  hipMemsetAsync(ws, 0, 65536, stream);   // ctr
  k_cvt_bf16<<<2048, 256, 0, stream>>>(input_, Xb, 16777216 / 4);
  k_cvt_bf16<<<1024, 256, 0, stream>>>(w_ih, Wihb, 3145728 / 4);
  k_cvt_bf16<<<1024, 256, 0, stream>>>(w_hh, Whhb, 3145728 / 4);
  k_cvt_bf16<<<1024, 256, 0, stream>>>(w_ch, Wchb, 3145728 / 4);
  k_cvt_bf16<<<1024, 256, 0, stream>>>(w_zh, Wzhb, 3145728 / 4);
  k_cvt_bf16<<<64, 256, 0, stream>>>(cj, cjb, 65536 / 4);
  k_cvt_bf16<<<64, 256, 0, stream>>>(he, heb, 65536 / 4);
  k_ctx<<<192, 256, 0, stream>>>(cjb, heb, Wchb, Wzhb, b_ih, b_hh, b_ch, b_zh, E);
  k_gemm_gi<<<3072, 256, 0, stream>>>(Xb, Wihb, E, gi);
  k_rnn<<<64, 1024, 0, stream>>>(gi, Whhb, b_hh, h0, length, hbuf, h0row, out, hn, ctr);
}

// Round 4
// 3993.983 us; speedup vs baseline: 2.3030x; 2.3030x over previous
//
#include <hip/hip_runtime.h>
#include <stdint.h>

#define TT 256
#define BB 64
#define DD 1024
#define HH 1024
#define G3 3072

typedef unsigned long long ull;
typedef __attribute__((ext_vector_type(8))) short short8;
typedef __attribute__((ext_vector_type(4))) float f32x4;

__device__ __forceinline__ unsigned short f2bf(float f) {
  union { float f; unsigned int i; } v; v.f = f;
  unsigned int x = v.i;
  return (unsigned short)((x + 0x7fffu + ((x >> 16) & 1u)) >> 16);
}
__device__ __forceinline__ float bf2f(unsigned short u) {
  union { unsigned int i; float f; } v; v.i = ((unsigned int)u) << 16; return v.f;
}
__device__ __forceinline__ f32x4 mfma16(short8 a, short8 b, f32x4 c) {
  return __builtin_amdgcn_mfma_f32_16x16x32_bf16(a, b, c, 0, 0, 0);
}
__device__ __forceinline__ void gload_lds16(const void* g, void* l) {
  __builtin_amdgcn_global_load_lds((const __attribute__((address_space(1))) void*)g,
                                   (__attribute__((address_space(3))) void*)l,
                                   16, 0, 0);
}

// ---------------- f32 -> bf16 convert (vectorized) ----------------
__global__ void k_cvt_bf16(const float* __restrict__ in, unsigned short* __restrict__ out, int n4) {
  int i = blockIdx.x * blockDim.x + threadIdx.x;
  int stride = gridDim.x * blockDim.x;
  for (; i < n4; i += stride) {
    float4 v = ((const float4*)in)[i];
    ushort4 o;
    o.x = f2bf(v.x); o.y = f2bf(v.y); o.z = f2bf(v.z); o.w = f2bf(v.w);
    ((ushort4*)out)[i] = o;
  }
}

// ---------------- context projections + bias fold: E[64][3072] ----------------
__global__ __launch_bounds__(256) void k_ctx(
    const unsigned short* __restrict__ cjb, const unsigned short* __restrict__ heb,
    const unsigned short* __restrict__ Wchb, const unsigned short* __restrict__ Wzhb,
    const float* __restrict__ b_ih, const float* __restrict__ b_hh,
    const float* __restrict__ b_ch, const float* __restrict__ b_zh,
    float* __restrict__ E) {
  __shared__ f32x4 red[4][4][64];   // 16 KB
  int n0 = blockIdx.x * 16;         // 192 blocks
  int tid = threadIdx.x;
  int w = tid >> 6, l = tid & 63, lo = l & 15, hi = l >> 4;
  f32x4 acc[4];
#pragma unroll
  for (int r = 0; r < 4; r++) acc[r] = (f32x4){0.f, 0.f, 0.f, 0.f};
#pragma unroll 4
  for (int kk = 0; kk < 16; kk++) {
    int k = w * 512 + kk * 32;
    const unsigned short* Asrc = (k < 1024) ? cjb : heb;
    const unsigned short* Bsrc = (k < 1024) ? Wchb : Wzhb;
    int kw = (k < 1024) ? k : (k - 1024);
    int kof = kw + hi * 8;
    short8 bf = *(const short8*)(Bsrc + (size_t)(n0 + lo) * 1024 + kof);
#pragma unroll
    for (int r = 0; r < 4; r++) {
      short8 af = *(const short8*)(Asrc + (size_t)(r * 16 + lo) * 1024 + kof);
      acc[r] = mfma16(af, bf, acc[r]);
    }
  }
#pragma unroll
  for (int r = 0; r < 4; r++) red[w][r][l] = acc[r];
  __syncthreads();
  f32x4 s = red[0][w][l];
#pragma unroll
  for (int w2 = 1; w2 < 4; w2++) {
    f32x4 p = red[w2][w][l];
    s[0] += p[0]; s[1] += p[1]; s[2] += p[2]; s[3] += p[3];
  }
  int g = n0 + lo;
  float bias = b_ih[g] + b_ch[g] + b_zh[g] + ((g < 2048) ? b_hh[g] : 0.0f);
#pragma unroll
  for (int j = 0; j < 4; j++) {
    int b = w * 16 + hi * 4 + j;
    E[(size_t)b * G3 + g] = s[j] + bias;
  }
}

// ---------------- gi GEMM + E fold: giE[t*64+b][g] = X@Wih^T + E[b][g] (bf16) --------
__global__ __launch_bounds__(256) void k_gemm_gi(
    const unsigned short* __restrict__ Xb,   // [16384][1024] bf16
    const unsigned short* __restrict__ Wb,   // [3072][1024] bf16
    const float* __restrict__ E,             // [64][3072] f32
    unsigned short* __restrict__ gi) {       // [16384][3072] bf16
  __shared__ unsigned short As[128 * 32];
  __shared__ unsigned short Bs[128 * 32];
  int bid = blockIdx.x;
  int mt = bid & 127;
  int nt = bid >> 7;
  int m0 = mt * 128, n0 = nt * 128;
  int tid = threadIdx.x;
  int w = tid >> 6, l = tid & 63, lo = l & 15, hi = l >> 4;
  int wr = w >> 1, wc = w & 1;
  f32x4 acc[4][4];
#pragma unroll
  for (int i = 0; i < 4; i++)
#pragma unroll
    for (int j = 0; j < 4; j++) acc[i][j] = (f32x4){0.f, 0.f, 0.f, 0.f};
  int srow = tid >> 2;
  int scol = (tid & 3) * 8;
  for (int kt = 0; kt < 32; kt++) {
    int k0 = kt * 32;
    __syncthreads();
    gload_lds16(Xb + (size_t)(m0 + srow) * 1024 + k0 + scol, As + srow * 32 + scol);
    gload_lds16(Xb + (size_t)(m0 + 64 + srow) * 1024 + k0 + scol, As + (64 + srow) * 32 + scol);
    gload_lds16(Wb + (size_t)(n0 + srow) * 1024 + k0 + scol, Bs + srow * 32 + scol);
    gload_lds16(Wb + (size_t)(n0 + 64 + srow) * 1024 + k0 + scol, Bs + (64 + srow) * 32 + scol);
    asm volatile("s_waitcnt vmcnt(0)" ::: "memory");
    __syncthreads();
    short8 a[4], b[4];
#pragma unroll
    for (int i = 0; i < 4; i++) a[i] = *(const short8*)(As + (wr * 64 + i * 16 + lo) * 32 + hi * 8);
#pragma unroll
    for (int i = 0; i < 4; i++) b[i] = *(const short8*)(Bs + (wc * 64 + i * 16 + lo) * 32 + hi * 8);
#pragma unroll
    for (int i = 0; i < 4; i++)
#pragma unroll
      for (int j = 0; j < 4; j++) acc[i][j] = mfma16(a[i], b[j], acc[i][j]);
  }
#pragma unroll
  for (int i = 0; i < 4; i++)
#pragma unroll
    for (int j = 0; j < 4; j++)
#pragma unroll
      for (int e = 0; e < 4; e++) {
        int r = m0 + wr * 64 + i * 16 + hi * 4 + e;
        int c = n0 + wc * 64 + j * 16 + lo;
        float v = acc[i][j][e] + E[(size_t)(r & 63) * G3 + c];
        gi[(size_t)r * G3 + c] = f2bf(v);
      }
}

// ---------------- persistent recurrence kernel ----------------
// 64 wgs x 1024 thr. wg cs owns h cols [cs*16,+16). 16 waves: rt = w&3 (row-tile),
// kq = w>>2 (K-slice). Updaters = kq==0 (waves 0-3). Wave 12 signals; wave 15 polls.
// ALL ordering relaxed; the compiler's pre-barrier vmcnt(0) drain orders stores
// before the signal. Signal: 1 fetch_add/wg/step to ctr[t][cs&7] (8 lines x 8 adds).
// Wait: wave 15 lanes poll the 8 read-mostly lines (no RMW contention vs r3).
__global__ __launch_bounds__(1024) void k_rnn(
    const unsigned short* __restrict__ giE,   // [256*64][3072] bf16 (incl E)
    const unsigned short* __restrict__ Whhb,  // [3072][1024] bf16
    const float* __restrict__ b_hh,
    const float* __restrict__ h0,
    const int* __restrict__ length,
    unsigned short* __restrict__ hbuf,        // [2][64][1024] bf16
    float* __restrict__ out,                  // [256][64][1024] f32
    float* __restrict__ hn,                   // [64][1024] f32
    unsigned int* __restrict__ ctr) {         // [256][8][16] uints (64B-spaced lines)
  __shared__ f32x4 red[16 * 3 * 64];          // 48 KB
  __shared__ float hp0[2][16];
  const int cs = blockIdx.x;
  const int j0 = cs * 16;
  const int tid = threadIdx.x;
  const int w = tid >> 6, l = tid & 63, lo = l & 15, hi = l >> 4;
  const int rt = w & 3, kq = w >> 2;
  const bool upd = (kq == 0);
  const int col = j0 + lo;
  const int rowbase = rt * 16;

  const unsigned short* wrp0 = Whhb + (size_t)col * 1024;
  const unsigned short* wrp1 = Whhb + (size_t)(1024 + col) * 1024;
  const unsigned short* wrp2 = Whhb + (size_t)(2048 + col) * 1024;
  const float bhhn = b_hh[2048 + col];

  float hown[4] = {0.f, 0.f, 0.f, 0.f};
  float gir[3][4], girN[3][4];
  int len4[4] = {0, 0, 0, 0};

  // ---- init: load h0 state, publish h(0) ----
  if (upd) {
#pragma unroll
    for (int j = 0; j < 4; j++) {
      int b = rowbase + hi * 4 + j;
      hown[j] = h0[(size_t)b * 1024 + col];
      len4[j] = length[b];
    }
#pragma unroll
    for (int j = 0; j < 4; j++) {
      unsigned int mine = f2bf(hown[j]);
      unsigned int oth = __shfl_xor(mine, 1, 64);
      if (!(lo & 1)) {
        int b = rowbase + hi * 4 + j;
        __hip_atomic_store((unsigned int*)(hbuf + (size_t)b * 1024 + j0 + lo),
                           mine | (oth << 16), __ATOMIC_RELAXED, __HIP_MEMORY_SCOPE_AGENT);
      }
    }
    if (rt == 0 && hi == 0) hp0[0][lo] = hown[0];
  }
  __syncthreads();   // compiler drain: h(0) stores complete before signal
  if (w == 12 && l == 0)
    __hip_atomic_fetch_add(&ctr[(cs & 7) * 16], 1u, __ATOMIC_RELAXED, __HIP_MEMORY_SCOPE_AGENT);
  if (upd) {
#pragma unroll
    for (int s = 0; s < 3; s++)
#pragma unroll
      for (int j = 0; j < 4; j++)
        gir[s][j] = bf2f(giE[(size_t)(rowbase + hi * 4 + j) * G3 + s * 1024 + col]);
  }

  for (int t = 0; t < TT; t++) {
    // ---- A: overlap window (runs during other wgs' catch-up + our poll) ----
    if (upd) {
      if (t > 0) {
        // out(t-1) = hown (h(t)); store off the critical path
#pragma unroll
        for (int j = 0; j < 4; j++) {
          int b = rowbase + hi * 4 + j;
          out[(size_t)(t - 1) * (BB * HH) + (size_t)b * 1024 + col] = hown[j];
        }
      }
      if (t < TT - 1) {
        const unsigned short* gb = giE + (size_t)(t + 1) * 64 * G3;
#pragma unroll
        for (int s = 0; s < 3; s++)
#pragma unroll
          for (int j = 0; j < 4; j++)
            girN[s][j] = bf2f(gb[(size_t)(rowbase + hi * 4 + j) * G3 + s * 1024 + col]);
      }
    }
    // ---- B: wait for step-t h to be published by all wgs (wave 15 polls) ----
    if (w == 15) {
      const unsigned int* cb = ctr + (size_t)t * 128 + (l & 7) * 16;
      for (;;) {
        unsigned int v = __hip_atomic_load(cb, __ATOMIC_RELAXED, __HIP_MEMORY_SCOPE_AGENT);
        if (__all(v >= 8u)) break;
        __builtin_amdgcn_s_sleep(2);
      }
    }
    __syncthreads();
    // ---- C: partial GEMM on h(t) ----
    const unsigned short* hb = hbuf + (size_t)(t & 1) * (BB * 1024);
    f32x4 a0 = {0.f, 0.f, 0.f, 0.f}, a1 = a0, a2 = a0;
#pragma unroll
    for (int kk = 0; kk < 8; kk++) {
      int k = kq * 256 + kk * 32 + hi * 8;
      const unsigned short* hp = hb + (size_t)(rowbase + lo) * 1024 + k;
      union { ull u[2]; short8 v; } a;
      a.u[0] = __hip_atomic_load((const ull*)hp, __ATOMIC_RELAXED, __HIP_MEMORY_SCOPE_AGENT);
      a.u[1] = __hip_atomic_load((const ull*)(hp + 4), __ATOMIC_RELAXED, __HIP_MEMORY_SCOPE_AGENT);
      short8 b0 = *(const short8*)(wrp0 + k);
      short8 b1 = *(const short8*)(wrp1 + k);
      short8 b2 = *(const short8*)(wrp2 + k);
      a0 = mfma16(a.v, b0, a0);
      a1 = mfma16(a.v, b1, a1);
      a2 = mfma16(a.v, b2, a2);
    }
    red[(w * 3 + 0) * 64 + l] = a0;
    red[(w * 3 + 1) * 64 + l] = a1;
    red[(w * 3 + 2) * 64 + l] = a2;
    __syncthreads();
    // ---- D: updaters reduce + gates + publish h(t+1) ----
    if (upd) {
      float h0p = hp0[t & 1][lo];
      f32x4 fin[3];
#pragma unroll
      for (int s = 0; s < 3; s++) {
        f32x4 v = red[((0 * 4 + rt) * 3 + s) * 64 + l];
#pragma unroll
        for (int kq2 = 1; kq2 < 4; kq2++) {
          f32x4 p = red[((kq2 * 4 + rt) * 3 + s) * 64 + l];
          v[0] += p[0]; v[1] += p[1]; v[2] += p[2]; v[3] += p[3];
        }
        fin[s] = v;
      }
      float hv[4];
#pragma unroll
      for (int j = 0; j < 4; j++) {
        float R = fin[0][j] + gir[0][j];
        float I = fin[1][j] + gir[1][j];
        float rg = 1.f / (1.f + __expf(-R));
        float ig = 1.f / (1.f + __expf(-I));
        float nx = gir[2][j] + rg * (fin[2][j] + bhhn);
        nx = fminf(15.f, fmaxf(-15.f, nx));
        float e2 = __expf(2.f * nx);
        float ng = (e2 - 1.f) / (e2 + 1.f);
        float hy = ng + ig * (hown[j] - ng);
        float res = (t < len4[j]) ? hy : h0p;
        hv[j] = res;
        hown[j] = res;
      }
      if (t < TT - 1) {
        unsigned short* dst = hbuf + (size_t)((t + 1) & 1) * (BB * 1024);
#pragma unroll
        for (int j = 0; j < 4; j++) {
          unsigned int mine = f2bf(hv[j]);
          unsigned int oth = __shfl_xor(mine, 1, 64);
          if (!(lo & 1)) {
            int b = rowbase + hi * 4 + j;
            __hip_atomic_store((unsigned int*)(dst + (size_t)b * 1024 + j0 + lo),
                               mine | (oth << 16), __ATOMIC_RELAXED, __HIP_MEMORY_SCOPE_AGENT);
          }
        }
        if (rt == 0 && hi == 0) hp0[(t + 1) & 1][lo] = hv[0];
      }
    }
    __syncthreads();   // compiler drain: h(t+1) stores complete before signal
    if (t < TT - 1) {
      if (w == 12 && l == 0)
        __hip_atomic_fetch_add(&ctr[(size_t)(t + 1) * 128 + (cs & 7) * 16], 1u,
                               __ATOMIC_RELAXED, __HIP_MEMORY_SCOPE_AGENT);
      if (upd) {
#pragma unroll
        for (int s = 0; s < 3; s++)
#pragma unroll
          for (int j = 0; j < 4; j++)
            gir[s][j] = girN[s][j];
      }
    }
  }
  // ---- tail: out(TT-1) + hn ----
  if (upd) {
#pragma unroll
    for (int j = 0; j < 4; j++) {
      int b = rowbase + hi * 4 + j;
      out[(size_t)(TT - 1) * (BB * HH) + (size_t)b * 1024 + col] = hown[j];
      hn[(size_t)b * 1024 + col] = hown[j];
    }
  }
}

// ---------------- host ----------------
extern "C" void kernel_launch(void* const* d_in, const int* in_sizes, int n_in,
                              void* d_out, int out_size, void* d_ws, size_t ws_size,
                              hipStream_t stream) {
  const float* input_ = (const float*)d_in[0];
  const int* length   = (const int*)d_in[1];
  const float* h0     = (const float*)d_in[2];
  const float* cj     = (const float*)d_in[3];
  const float* he     = (const float*)d_in[4];
  const float* w_ih   = (const float*)d_in[5];
  const float* w_hh   = (const float*)d_in[6];
  const float* w_ch   = (const float*)d_in[7];
  const float* w_zh   = (const float*)d_in[8];
  const float* b_ih   = (const float*)d_in[9];
  const float* b_hh   = (const float*)d_in[10];
  const float* b_ch   = (const float*)d_in[11];
  const float* b_zh   = (const float*)d_in[12];

  char* ws = (char*)d_ws;
  const size_t OFF_CTR   = 0;              // 131072 B: [256][8][16] uints
  const size_t OFF_XB    = 131072;
  const size_t OFF_WIHB  = OFF_XB + 33554432ull;
  const size_t OFF_WHHB  = OFF_WIHB + 6291456ull;
  const size_t OFF_WCHB  = OFF_WHHB + 6291456ull;
  const size_t OFF_WZHB  = OFF_WCHB + 6291456ull;
  const size_t OFF_CJB   = OFF_WZHB + 6291456ull;
  const size_t OFF_HEB   = OFF_CJB + 131072ull;
  const size_t OFF_E     = OFF_HEB + 131072ull;
  const size_t OFF_GI    = OFF_E + 786432ull;
  const size_t OFF_HBUF  = OFF_GI + 100663296ull;

  unsigned int* ctr     = (unsigned int*)(ws + OFF_CTR);
  unsigned short* Xb    = (unsigned short*)(ws + OFF_XB);
  unsigned short* Wihb  = (unsigned short*)(ws + OFF_WIHB);
  unsigned short* Whhb  = (unsigned short*)(ws + OFF_WHHB);
  unsigned short* Wchb  = (unsigned short*)(ws + OFF_WCHB);
  unsigned short* Wzhb  = (unsigned short*)(ws + OFF_WZHB);
  unsigned short* cjb   = (unsigned short*)(ws + OFF_CJB);
  unsigned short* heb   = (unsigned short*)(ws + OFF_HEB);
  float* E              = (float*)(ws + OFF_E);
  unsigned short* gi    = (unsigned short*)(ws + OFF_GI);
  unsigned short* hbuf  = (unsigned short*)(ws + OFF_HBUF);

  float* out = (float*)d_out;
  float* hn  = out + 16777216;   // T*B*H

  hipMemsetAsync(ctr, 0, 131072, stream);
  k_cvt_bf16<<<2048, 256, 0, stream>>>(input_, Xb, 16777216 / 4);
  k_cvt_bf16<<<1024, 256, 0, stream>>>(w_ih, Wihb, 3145728 / 4);
  k_cvt_bf16<<<1024, 256, 0, stream>>>(w_hh, Whhb, 3145728 / 4);
  k_cvt_bf16<<<1024, 256, 0, stream>>>(w_ch, Wchb, 3145728 / 4);
  k_cvt_bf16<<<1024, 256, 0, stream>>>(w_zh, Wzhb, 3145728 / 4);
  k_cvt_bf16<<<64, 256, 0, stream>>>(cj, cjb, 65536 / 4);
  k_cvt_bf16<<<64, 256, 0, stream>>>(he, heb, 65536 / 4);
  k_ctx<<<192, 256, 0, stream>>>(cjb, heb, Wchb, Wzhb, b_ih, b_hh, b_ch, b_zh, E);
  k_gemm_gi<<<3072, 256, 0, stream>>>(Xb, Wihb, E, gi);
  k_rnn<<<64, 1024, 0, stream>>>(gi, Whhb, b_hh, h0, length, hbuf, out, hn, ctr);
}